// Round 1
// baseline (1949.794 us; speedup 1.0000x reference)
//
#include <hip/hip_runtime.h>
#include <cstdint>
#include <cstddef>

// ---------- types / helpers ----------
typedef __attribute__((ext_vector_type(8))) short bf16x8;   // 8 bf16 = 4 VGPRs (MFMA A/B frag)
typedef __attribute__((ext_vector_type(4))) float f32x4;    // MFMA C/D frag

__device__ __forceinline__ unsigned short f2bf(float x) {
    union { float f; unsigned u; } v; v.f = x;
    unsigned r = (v.u + 0x7fffu + ((v.u >> 16) & 1u)) >> 16;   // RNE, inputs finite
    return (unsigned short)r;
}
__device__ __forceinline__ float b2f(unsigned short u) {
    union { unsigned u; float f; } v; v.u = ((unsigned)u) << 16; return v.f;
}
__device__ __forceinline__ float bflo(unsigned u){ union{unsigned i;float f;}v; v.i = u << 16;        return v.f; }
__device__ __forceinline__ float bfhi(unsigned u){ union{unsigned i;float f;}v; v.i = u & 0xffff0000u; return v.f; }

#define BB 64
#define TT 512
#define MM (BB*TT)     // 32768 rows
#define NG 1024        // 4H * 2 directions

// ---------- prep: embedding gather -> bf16, weight/bias concat+convert ----------
__global__ void prep_kernel(
    const int* __restrict__ sentences, const float* __restrict__ emb,
    const float* __restrict__ w_ih_l0, const float* __restrict__ w_ih_l0r,
    const float* __restrict__ w_ih_l1, const float* __restrict__ w_ih_l1r,
    const float* __restrict__ b_ih_l0, const float* __restrict__ b_hh_l0,
    const float* __restrict__ b_ih_l0r, const float* __restrict__ b_hh_l0r,
    const float* __restrict__ b_ih_l1, const float* __restrict__ b_hh_l1,
    const float* __restrict__ b_ih_l1r, const float* __restrict__ b_hh_l1r,
    unsigned short* __restrict__ x0, unsigned short* __restrict__ W0c,
    unsigned short* __restrict__ W1c, float* __restrict__ bias0, float* __restrict__ bias1)
{
    int blk = blockIdx.x;
    if (blk < 4096) {                       // gather: 32768 x 128, 4 elems/thread
        int t = blk * 256 + threadIdx.x;
        int e4 = t * 4; int m = e4 >> 7; int k = e4 & 127;
        int s = sentences[m];
        float4 v = *(const float4*)(emb + (size_t)s * 128 + k);
        *(ushort4*)(x0 + (size_t)m * 128 + k) =
            make_ushort4(f2bf(v.x), f2bf(v.y), f2bf(v.z), f2bf(v.w));
    } else if (blk < 4224) {                // W0cat: 1024 x 128
        int t = (blk - 4096) * 256 + threadIdx.x;
        int e4 = t * 4; int n = e4 >> 7; int k = e4 & 127;
        const float* src = (n < 512) ? (w_ih_l0 + (size_t)n * 128) : (w_ih_l0r + (size_t)(n - 512) * 128);
        float4 v = *(const float4*)(src + k);
        *(ushort4*)(W0c + (size_t)n * 128 + k) =
            make_ushort4(f2bf(v.x), f2bf(v.y), f2bf(v.z), f2bf(v.w));
    } else if (blk < 4480) {                // W1cat: 1024 x 256
        int t = (blk - 4224) * 256 + threadIdx.x;
        int e4 = t * 4; int n = e4 >> 8; int k = e4 & 255;
        const float* src = (n < 512) ? (w_ih_l1 + (size_t)n * 256) : (w_ih_l1r + (size_t)(n - 512) * 256);
        float4 v = *(const float4*)(src + k);
        *(ushort4*)(W1c + (size_t)n * 256 + k) =
            make_ushort4(f2bf(v.x), f2bf(v.y), f2bf(v.z), f2bf(v.w));
    } else {                                // biases: 2048 threads
        int t = (blk - 4480) * 256 + threadIdx.x;
        if (t < 1024) {
            bias0[t] = (t < 512) ? (b_ih_l0[t] + b_hh_l0[t]) : (b_ih_l0r[t - 512] + b_hh_l0r[t - 512]);
        } else {
            int n = t - 1024;
            bias1[n] = (n < 512) ? (b_ih_l1[n] + b_hh_l1[n]) : (b_ih_l1r[n - 512] + b_hh_l1r[n - 512]);
        }
    }
}

// ---------- GEMM: xg[m][n] = sum_k X[m][k]*W[n][k] + bias[n]  (bf16 MFMA) ----------
// A-operand = W tile (rows n), B-operand = X tile (rows m, as B[k][m'])
// D[row=n][col=m]: lane holds fixed m, regs = 4 consecutive n -> contiguous 8B stores.
__global__ __launch_bounds__(256, 2) void gemm_xg(
    const unsigned short* __restrict__ W,   // [NG][K]
    const unsigned short* __restrict__ X,   // [MM][K]
    const float* __restrict__ bias,         // [NG]
    unsigned short* __restrict__ xg,        // [MM][NG]
    int K)
{
    __shared__ unsigned short sW[128 * 32];
    __shared__ unsigned short sX[128 * 32];
    const int tid  = threadIdx.x;
    const int lane = tid & 63;
    const int wid  = tid >> 6;
    const int w_n  = wid & 1, w_m = wid >> 1;
    const int r16  = lane & 15, quad = lane >> 4;
    const int nTile = blockIdx.x * 128;
    const int mTile = blockIdx.y * 128;

    f32x4 zero = {0.f, 0.f, 0.f, 0.f};
    f32x4 acc[4][4];
    #pragma unroll
    for (int i = 0; i < 4; ++i)
        #pragma unroll
        for (int j = 0; j < 4; ++j) acc[i][j] = zero;

    const int q0 = tid, q1 = tid + 256;                 // 16B-chunk ids (512 per 8KB tile)
    const int r0 = q0 >> 2, ko0 = (q0 & 3) * 8;
    const int r1 = q1 >> 2, ko1 = (q1 & 3) * 8;

    for (int k0 = 0; k0 < K; k0 += 32) {
        __syncthreads();
        uint4 wv0 = *(const uint4*)(W + (size_t)(nTile + r0) * K + k0 + ko0);
        uint4 wv1 = *(const uint4*)(W + (size_t)(nTile + r1) * K + k0 + ko1);
        uint4 xv0 = *(const uint4*)(X + (size_t)(mTile + r0) * K + k0 + ko0);
        uint4 xv1 = *(const uint4*)(X + (size_t)(mTile + r1) * K + k0 + ko1);
        ((uint4*)sW)[q0] = wv0;
        ((uint4*)sW)[q1] = wv1;
        ((uint4*)sX)[q0] = xv0;
        ((uint4*)sX)[q1] = xv1;
        __syncthreads();
        const bf16x8* sWv = (const bf16x8*)sW;
        const bf16x8* sXv = (const bf16x8*)sX;
        bf16x8 a[4], bx[4];
        #pragma unroll
        for (int i = 0; i < 4; ++i) {
            a[i]  = sWv[(w_n * 64 + i * 16 + r16) * 4 + quad];
            bx[i] = sXv[(w_m * 64 + i * 16 + r16) * 4 + quad];
        }
        #pragma unroll
        for (int i = 0; i < 4; ++i)
            #pragma unroll
            for (int j = 0; j < 4; ++j)
                acc[i][j] = __builtin_amdgcn_mfma_f32_16x16x32_bf16(a[i], bx[j], acc[i][j], 0, 0, 0);
    }

    #pragma unroll
    for (int i = 0; i < 4; ++i) {
        int nb = nTile + w_n * 64 + i * 16 + quad * 4;
        float4 bv = *(const float4*)(bias + nb);
        #pragma unroll
        for (int j = 0; j < 4; ++j) {
            int mg = mTile + w_m * 64 + j * 16 + r16;
            f32x4 v = acc[i][j];
            ushort4 o = make_ushort4(f2bf(v.x + bv.x), f2bf(v.y + bv.y),
                                     f2bf(v.z + bv.z), f2bf(v.w + bv.w));
            *(ushort4*)(xg + (size_t)mg * NG + nb) = o;
        }
    }
}

// ---------- LSTM scan: one workgroup per (direction, batch) chain ----------
// thread j owns gate-row j; w_hh row j lives in 32 float4 VGPRs; h broadcast via LDS.
__global__ __launch_bounds__(512, 2) void lstm_scan(
    const unsigned short* __restrict__ xg,   // [MM][1024], col = dir*512 + j
    const float* __restrict__ whh_f,         // (512,128) fwd
    const float* __restrict__ whh_r,         // (512,128) rev
    unsigned short* __restrict__ xnext)      // [MM][256], col = dir*128 + u
{
    const int blk = blockIdx.x;
    const int dir = blk >> 6;
    const int b   = blk & 63;
    const int j   = threadIdx.x;
    const float* whh = dir ? whh_r : whh_f;

    float4 wr[32];
    {
        const float4* wrow = (const float4*)(whh + (size_t)j * 128);
        #pragma unroll
        for (int k = 0; k < 32; ++k) wr[k] = wrow[k];
    }

    __shared__ float h_lds[128];
    __shared__ float gates[512];
    if (j < 128) h_lds[j] = 0.f;
    float c = 0.f;
    __syncthreads();

    const unsigned short* xgp = xg + (size_t)b * 512 * 1024 + (size_t)dir * 512 + j;
    unsigned short* outp = xnext + (size_t)b * 512 * 256 + (size_t)dir * 128 + (j & 127);

    for (int s = 0; s < 512; ++s) {
        const int t = dir ? (511 - s) : s;
        float xv = b2f(xgp[(size_t)t * 1024]);       // issued early, consumed after dot
        float a0 = 0.f, a1 = 0.f, a2 = 0.f, a3 = 0.f;
        const float4* h4p = (const float4*)h_lds;
        #pragma unroll
        for (int k = 0; k < 32; ++k) {
            float4 h4 = h4p[k];                      // ds_read_b128 broadcast
            a0 += wr[k].x * h4.x;
            a1 += wr[k].y * h4.y;
            a2 += wr[k].z * h4.z;
            a3 += wr[k].w * h4.w;
        }
        gates[j] = xv + ((a0 + a1) + (a2 + a3));
        __syncthreads();
        if (j < 128) {
            float ig = gates[j];
            float fg = gates[j + 128];
            float gg = gates[j + 256];
            float og = gates[j + 384];
            float iS = 1.f / (1.f + __expf(-ig));
            float fS = 1.f / (1.f + __expf(-fg));
            float oS = 1.f / (1.f + __expf(-og));
            float gT = tanhf(gg);
            c = fS * c + iS * gT;
            float h = oS * tanhf(c);
            h_lds[j] = h;
            outp[(size_t)t * 256] = f2bf(h);
        }
        __syncthreads();
    }
}

// ---------- emissions: [MM][8] = x2(bf16) @ h2t_w^T + h2t_b ----------
__global__ void emis_kernel(const unsigned short* __restrict__ x2,
                            const float* __restrict__ h2t_w,
                            const float* __restrict__ h2t_b,
                            float* __restrict__ emis)
{
    int idx = blockIdx.x * 256 + threadIdx.x;   // m*8 + tag
    int m = idx >> 3, tag = idx & 7;
    const unsigned short* xr = x2 + (size_t)m * 256;
    const float* wr = h2t_w + (size_t)tag * 256;
    float a0 = 0.f, a1 = 0.f, a2 = 0.f, a3 = 0.f;
    #pragma unroll 4
    for (int k = 0; k < 256; k += 8) {
        uint4 xv = *(const uint4*)(xr + k);
        float4 w0 = *(const float4*)(wr + k);
        float4 w1 = *(const float4*)(wr + k + 4);
        a0 += bflo(xv.x) * w0.x + bfhi(xv.x) * w0.y;
        a1 += bflo(xv.y) * w0.z + bfhi(xv.y) * w0.w;
        a2 += bflo(xv.z) * w1.x + bfhi(xv.z) * w1.y;
        a3 += bflo(xv.w) * w1.z + bfhi(xv.w) * w1.w;
    }
    emis[idx] = h2t_b[tag] + ((a0 + a1) + (a2 + a3));
}

// ---------- CRF: per-sample partition (8x8 = 64 lanes) + gold score ----------
__global__ void crf_kernel(const float* __restrict__ emis,   // [BB][TT][8]
                           const int* __restrict__ tags,     // [BB][TT]
                           const float* __restrict__ trans,  // [8][8]
                           float* __restrict__ partials)     // [BB]
{
    const int b = blockIdx.x;
    const int l = threadIdx.x;                 // 64 lanes: (i = l>>3, j = l&7)
    const float* eb = emis + (size_t)b * TT * 8;
    const int i = l >> 3, j = l & 7;
    const float tij = trans[i * 8 + j];

    float fv = eb[i];                           // fv[i] at t=0
    for (int t = 1; t < TT; ++t) {
        float v = fv + tij + eb[t * 8 + j];
        float m = v;
        m = fmaxf(m, __shfl_xor(m, 8));
        m = fmaxf(m, __shfl_xor(m, 16));
        m = fmaxf(m, __shfl_xor(m, 32));
        float e = __expf(v - m);
        e += __shfl_xor(e, 8);
        e += __shfl_xor(e, 16);
        e += __shfl_xor(e, 32);
        float fvj = m + __logf(e);              // lanes in column-group j hold fv_new[j]
        fv = __shfl(fvj, i);                    // lane (l>>3) has fv_new[l>>3]
    }
    // partition = lse_j fv[j]; groups of 8 lanes hold each value -> mask to one rep
    float x = ((l & 7) == 0) ? fv : -1e30f;
    float m2 = x;
    #pragma unroll
    for (int d = 1; d < 64; d <<= 1) m2 = fmaxf(m2, __shfl_xor(m2, d));
    float e2 = ((l & 7) == 0) ? __expf(x - m2) : 0.f;
    #pragma unroll
    for (int d = 1; d < 64; d <<= 1) e2 += __shfl_xor(e2, d);
    float partition = m2 + __logf(e2);

    // gold scores
    const int* tg = tags + (size_t)b * TT;
    float sc = 0.f;
    for (int t = l; t < TT; t += 64) sc += eb[t * 8 + tg[t]];
    for (int t = l + 1; t < TT; t += 64) sc += trans[tg[t - 1] * 8 + tg[t]];
    #pragma unroll
    for (int d = 1; d < 64; d <<= 1) sc += __shfl_xor(sc, d);

    if (l == 0) partials[b] = sc - partition;
}

__global__ void final_kernel(const float* __restrict__ partials, float* __restrict__ out)
{
    int l = threadIdx.x;
    float v = partials[l];
    #pragma unroll
    for (int d = 1; d < 64; d <<= 1) v += __shfl_xor(v, d);
    if (l == 0) out[0] = -v / 64.f;
}

// ---------- launch ----------
extern "C" void kernel_launch(void* const* d_in, const int* in_sizes, int n_in,
                              void* d_out, int out_size, void* d_ws, size_t ws_size,
                              hipStream_t stream)
{
    const int*   sentences = (const int*)d_in[0];
    const int*   tags      = (const int*)d_in[1];
    const float* embedding = (const float*)d_in[2];
    const float* w_ih_l0   = (const float*)d_in[3];
    const float* w_hh_l0   = (const float*)d_in[4];
    const float* b_ih_l0   = (const float*)d_in[5];
    const float* b_hh_l0   = (const float*)d_in[6];
    const float* w_ih_l0r  = (const float*)d_in[7];
    const float* w_hh_l0r  = (const float*)d_in[8];
    const float* b_ih_l0r  = (const float*)d_in[9];
    const float* b_hh_l0r  = (const float*)d_in[10];
    const float* w_ih_l1   = (const float*)d_in[11];
    const float* w_hh_l1   = (const float*)d_in[12];
    const float* b_ih_l1   = (const float*)d_in[13];
    const float* b_hh_l1   = (const float*)d_in[14];
    const float* w_ih_l1r  = (const float*)d_in[15];
    const float* w_hh_l1r  = (const float*)d_in[16];
    const float* b_ih_l1r  = (const float*)d_in[17];
    const float* b_hh_l1r  = (const float*)d_in[18];
    const float* h2t_w     = (const float*)d_in[19];
    const float* h2t_b     = (const float*)d_in[20];
    const float* trans     = (const float*)d_in[21];

    char* ws = (char*)d_ws;
    unsigned short* xg  = (unsigned short*)(ws);                 // 67,108,864 B
    unsigned short* x0  = (unsigned short*)(ws + 67108864);      //  8,388,608 B
    unsigned short* x1  = (unsigned short*)(ws + 75497472);      // 16,777,216 B
    unsigned short* x2  = (unsigned short*)(ws + 92274688);      // 16,777,216 B
    unsigned short* W0c = (unsigned short*)(ws + 109051904);     //    262,144 B
    unsigned short* W1c = (unsigned short*)(ws + 109314048);     //    524,288 B
    float* bias0        = (float*)(ws + 109838336);              //      4,096 B
    float* bias1        = (float*)(ws + 109842432);              //      4,096 B
    float* emis         = (float*)(ws + 109846528);              //  1,048,576 B
    float* partials     = (float*)(ws + 110895104);              //        256 B
    (void)ws_size; (void)in_sizes; (void)n_in; (void)out_size;

    prep_kernel<<<4488, 256, 0, stream>>>(sentences, embedding,
        w_ih_l0, w_ih_l0r, w_ih_l1, w_ih_l1r,
        b_ih_l0, b_hh_l0, b_ih_l0r, b_hh_l0r,
        b_ih_l1, b_hh_l1, b_ih_l1r, b_hh_l1r,
        x0, W0c, W1c, bias0, bias1);

    gemm_xg<<<dim3(8, 256), 256, 0, stream>>>(W0c, x0, bias0, xg, 128);
    lstm_scan<<<128, 512, 0, stream>>>(xg, w_hh_l0, w_hh_l0r, x1);
    gemm_xg<<<dim3(8, 256), 256, 0, stream>>>(W1c, x1, bias1, xg, 256);
    lstm_scan<<<128, 512, 0, stream>>>(xg, w_hh_l1, w_hh_l1r, x2);
    emis_kernel<<<1024, 256, 0, stream>>>(x2, h2t_w, h2t_b, emis);
    crf_kernel<<<64, 64, 0, stream>>>(emis, tags, trans, partials);
    final_kernel<<<1, 64, 0, stream>>>(partials, (float*)d_out);
}

// Round 2
// 1331.906 us; speedup vs baseline: 1.4639x; 1.4639x over previous
//
#include <hip/hip_runtime.h>
#include <cstdint>
#include <cstddef>

// ---------- types / helpers ----------
typedef __attribute__((ext_vector_type(8))) short bf16x8;   // 8 bf16 = 4 VGPRs (MFMA A/B frag)
typedef __attribute__((ext_vector_type(4))) float f32x4;    // MFMA C/D frag

__device__ __forceinline__ unsigned short f2bf(float x) {
    union { float f; unsigned u; } v; v.f = x;
    unsigned r = (v.u + 0x7fffu + ((v.u >> 16) & 1u)) >> 16;   // RNE, inputs finite
    return (unsigned short)r;
}
__device__ __forceinline__ float bflo(unsigned u){ union{unsigned i;float f;}v; v.i = u << 16;        return v.f; }
__device__ __forceinline__ float bfhi(unsigned u){ union{unsigned i;float f;}v; v.i = u & 0xffff0000u; return v.f; }

__device__ __forceinline__ float frcp(float x){ return __builtin_amdgcn_rcpf(x); }
__device__ __forceinline__ float fsig(float x){ return frcp(1.f + __expf(-x)); }
__device__ __forceinline__ float ftanh(float x){ return 1.f - 2.f * frcp(1.f + __expf(2.f * x)); }

#define BB 64
#define TT 512
#define MM (BB*TT)     // 32768 rows (time-major: m = t*64 + b)
#define NG 1024        // 4H * 2 directions (permuted gate order)

// Gate permutation (per direction): g'' = w*64 + gtype*16 + uo  <->  orig = gtype*128 + w*16 + uo
// so scan-wave w's 64 rows = units [16w..16w+15] x {i,f,g,o}  -> i/f/g/o land in one lane's regs.
__device__ __forceinline__ int perm_orig(int g2) {
    return ((g2 >> 4) & 3) * 128 + (g2 >> 6) * 16 + (g2 & 15);
}

// ---------- prep: gather (time-major) + permuted weight/bias convert ----------
__global__ void prep_kernel(
    const int* __restrict__ sentences, const float* __restrict__ emb,
    const float* __restrict__ w_ih_l0, const float* __restrict__ w_ih_l0r,
    const float* __restrict__ w_ih_l1, const float* __restrict__ w_ih_l1r,
    const float* __restrict__ w_hh_l0, const float* __restrict__ w_hh_l0r,
    const float* __restrict__ w_hh_l1, const float* __restrict__ w_hh_l1r,
    const float* __restrict__ b_ih_l0, const float* __restrict__ b_hh_l0,
    const float* __restrict__ b_ih_l0r, const float* __restrict__ b_hh_l0r,
    const float* __restrict__ b_ih_l1, const float* __restrict__ b_hh_l1,
    const float* __restrict__ b_ih_l1r, const float* __restrict__ b_hh_l1r,
    unsigned short* __restrict__ x0, unsigned short* __restrict__ W0c,
    unsigned short* __restrict__ W1c,
    unsigned short* __restrict__ Whh0c, unsigned short* __restrict__ Whh1c,
    float* __restrict__ bias0, float* __restrict__ bias1)
{
    int blk = blockIdx.x;
    if (blk < 4096) {                       // gather: 32768 x 128, time-major rows
        int t4 = blk * 256 + threadIdx.x;
        int e4 = t4 * 4; int m = e4 >> 7; int k = e4 & 127;
        int tt = m >> 6, b = m & 63;
        int s = sentences[b * 512 + tt];
        float4 v = *(const float4*)(emb + (size_t)s * 128 + k);
        *(ushort4*)(x0 + (size_t)m * 128 + k) =
            make_ushort4(f2bf(v.x), f2bf(v.y), f2bf(v.z), f2bf(v.w));
    } else if (blk < 4224) {                // W0c: 1024 x 128, permuted rows
        int t4 = (blk - 4096) * 256 + threadIdx.x;
        int e4 = t4 * 4; int n = e4 >> 7; int k = e4 & 127;
        int dir = n >> 9; int orig = perm_orig(n & 511);
        const float* src = dir ? w_ih_l0r : w_ih_l0;
        float4 v = *(const float4*)(src + (size_t)orig * 128 + k);
        *(ushort4*)(W0c + (size_t)n * 128 + k) =
            make_ushort4(f2bf(v.x), f2bf(v.y), f2bf(v.z), f2bf(v.w));
    } else if (blk < 4480) {                // W1c: 1024 x 256, permuted rows
        int t4 = (blk - 4224) * 256 + threadIdx.x;
        int e4 = t4 * 4; int n = e4 >> 8; int k = e4 & 255;
        int dir = n >> 9; int orig = perm_orig(n & 511);
        const float* src = dir ? w_ih_l1r : w_ih_l1;
        float4 v = *(const float4*)(src + (size_t)orig * 256 + k);
        *(ushort4*)(W1c + (size_t)n * 256 + k) =
            make_ushort4(f2bf(v.x), f2bf(v.y), f2bf(v.z), f2bf(v.w));
    } else if (blk < 4608) {                // Whh0c: [2][512][128] bf16, permuted rows
        int t4 = (blk - 4480) * 256 + threadIdx.x;
        int e4 = t4 * 4; int n = e4 >> 7; int k = e4 & 127;
        int dir = n >> 9; int orig = perm_orig(n & 511);
        const float* src = dir ? w_hh_l0r : w_hh_l0;
        float4 v = *(const float4*)(src + (size_t)orig * 128 + k);
        *(ushort4*)(Whh0c + (size_t)n * 128 + k) =
            make_ushort4(f2bf(v.x), f2bf(v.y), f2bf(v.z), f2bf(v.w));
    } else if (blk < 4736) {                // Whh1c
        int t4 = (blk - 4608) * 256 + threadIdx.x;
        int e4 = t4 * 4; int n = e4 >> 7; int k = e4 & 127;
        int dir = n >> 9; int orig = perm_orig(n & 511);
        const float* src = dir ? w_hh_l1r : w_hh_l1;
        float4 v = *(const float4*)(src + (size_t)orig * 128 + k);
        *(ushort4*)(Whh1c + (size_t)n * 128 + k) =
            make_ushort4(f2bf(v.x), f2bf(v.y), f2bf(v.z), f2bf(v.w));
    } else {                                // biases: 2048 values, permuted
        int t = (blk - 4736) * 256 + threadIdx.x;
        int n = t & 1023;
        int dir = n >> 9; int orig = perm_orig(n & 511);
        if (t < 1024)
            bias0[n] = dir ? (b_ih_l0r[orig] + b_hh_l0r[orig]) : (b_ih_l0[orig] + b_hh_l0[orig]);
        else
            bias1[n] = dir ? (b_ih_l1r[orig] + b_hh_l1r[orig]) : (b_ih_l1[orig] + b_hh_l1[orig]);
    }
}

// ---------- GEMM: xg[m][n] = sum_k X[m][k]*W[n][k] + bias[n]  (bf16 MFMA) ----------
// Epilogue writes xgS in scan-fragment order:
//   off(ushort) = (t*2+dir)*32768 + bg*8192 + w*1024 + tile*256 + lane*4
// where n = dir*512+g2, g2 = w*64+tile*16+quad*4+r; m = t*64 + (bg*16+bl), lane = quad*16+bl.
__global__ __launch_bounds__(256, 2) void gemm_xg(
    const unsigned short* __restrict__ W,   // [NG][K] permuted rows
    const unsigned short* __restrict__ X,   // [MM][K] time-major
    const float* __restrict__ bias,         // [NG] permuted
    unsigned short* __restrict__ xgS,       // fragment-ordered, 64 MB
    int K)
{
    __shared__ unsigned short sW[128 * 32];
    __shared__ unsigned short sX[128 * 32];
    const int tid  = threadIdx.x;
    const int lane = tid & 63;
    const int wid  = tid >> 6;
    const int w_n  = wid & 1, w_m = wid >> 1;
    const int r16  = lane & 15, quad = lane >> 4;
    const int nTile = blockIdx.x * 128;
    const int mTile = blockIdx.y * 128;

    f32x4 zero = {0.f, 0.f, 0.f, 0.f};
    f32x4 acc[4][4];
    #pragma unroll
    for (int i = 0; i < 4; ++i)
        #pragma unroll
        for (int j = 0; j < 4; ++j) acc[i][j] = zero;

    const int q0 = tid, q1 = tid + 256;
    const int r0 = q0 >> 2, ko0 = (q0 & 3) * 8;
    const int r1 = q1 >> 2, ko1 = (q1 & 3) * 8;

    for (int k0 = 0; k0 < K; k0 += 32) {
        __syncthreads();
        uint4 wv0 = *(const uint4*)(W + (size_t)(nTile + r0) * K + k0 + ko0);
        uint4 wv1 = *(const uint4*)(W + (size_t)(nTile + r1) * K + k0 + ko1);
        uint4 xv0 = *(const uint4*)(X + (size_t)(mTile + r0) * K + k0 + ko0);
        uint4 xv1 = *(const uint4*)(X + (size_t)(mTile + r1) * K + k0 + ko1);
        ((uint4*)sW)[q0] = wv0;
        ((uint4*)sW)[q1] = wv1;
        ((uint4*)sX)[q0] = xv0;
        ((uint4*)sX)[q1] = xv1;
        __syncthreads();
        const bf16x8* sWv = (const bf16x8*)sW;
        const bf16x8* sXv = (const bf16x8*)sX;
        bf16x8 a[4], bx[4];
        #pragma unroll
        for (int i = 0; i < 4; ++i) {
            a[i]  = sWv[(w_n * 64 + i * 16 + r16) * 4 + quad];
            bx[i] = sXv[(w_m * 64 + i * 16 + r16) * 4 + quad];
        }
        #pragma unroll
        for (int i = 0; i < 4; ++i)
            #pragma unroll
            for (int j = 0; j < 4; ++j)
                acc[i][j] = __builtin_amdgcn_mfma_f32_16x16x32_bf16(a[i], bx[j], acc[i][j], 0, 0, 0);
    }

    #pragma unroll
    for (int i = 0; i < 4; ++i) {
        int nb = nTile + w_n * 64 + i * 16 + quad * 4;    // permuted global col, 4 regs
        float4 bv = *(const float4*)(bias + nb);
        int dir = nb >> 9, g2 = nb & 511;
        int sw = g2 >> 6, tile = (g2 >> 4) & 3;           // quad == (g2>>2)&3
        #pragma unroll
        for (int j = 0; j < 4; ++j) {
            int m = mTile + w_m * 64 + j * 16 + r16;
            int t = m >> 6, b = m & 63;
            f32x4 v = acc[i][j];
            ushort4 o = make_ushort4(f2bf(v.x + bv.x), f2bf(v.y + bv.y),
                                     f2bf(v.z + bv.z), f2bf(v.w + bv.w));
            size_t off = (size_t)(t * 2 + dir) * 32768 + (size_t)(b >> 4) * 8192
                       + sw * 1024 + tile * 256 + (quad * 16 + (b & 15)) * 4;
            *(ushort4*)(xgS + off) = o;
        }
    }
}

// ---------- MFMA LSTM scan: 16 batch-chains per block, 8 blocks per layer ----------
// wave w: A = 64 permuted W_hh rows (units 16w..16w+15 x {i,f,g,o}) in 64 VGPRs;
// B = h[16 x 128] from LDS (fragment-ordered, double-buffered); 16 MFMA/step.
// lane (q,bl) owns gates i/f/g/o of units 16w+4q..+3 for batch bl -> c[] local, no gate LDS.
__global__ __launch_bounds__(512, 1) void lstm_scan_mfma(
    const unsigned short* __restrict__ xgS,
    const unsigned short* __restrict__ whh_c,   // [2][512 perm rows][128] bf16
    unsigned short* __restrict__ xnext)         // [MM][256], col = dir*128 + u
{
    const int dir = blockIdx.x >> 2;
    const int bg  = blockIdx.x & 3;
    const int tid = threadIdx.x;
    const int w   = tid >> 6;
    const int lane= tid & 63;
    const int q   = lane >> 4;
    const int bl  = lane & 15;

    // weights -> A-frags (held in registers for all 512 steps)
    bf16x8 afrag[4][4];
    {
        const unsigned short* wb = whh_c + (size_t)dir * 512 * 128;
        #pragma unroll
        for (int tp = 0; tp < 4; ++tp)
            #pragma unroll
            for (int kk = 0; kk < 4; ++kk)
                afrag[tp][kk] = *(const bf16x8*)(wb + (size_t)(w * 64 + tp * 16 + bl) * 128 + kk * 32 + q * 8);
    }

    __shared__ unsigned short hbuf[2][2048];     // h in B-fragment order, double-buffered
    *(ushort4*)(&hbuf[1][tid * 4]) = make_ushort4(0, 0, 0, 0);   // h(-1) = 0

    const int uu = w * 16 + q * 4;               // this lane's first unit
    const int hwoff = (uu >> 5) * 512 + (((uu >> 3) & 3) * 16 + bl) * 8 + (uu & 7); // ushort idx

    float c[4] = {0.f, 0.f, 0.f, 0.f};

    const int t0 = dir ? 511 : 0;
    const long tstep = dir ? -65536 : 65536;     // ushorts per t step
    long xoff = (long)(2 * t0 + dir) * 32768 + bg * 8192 + w * 1024 + lane * 4;

    uint2 cur[4], nxt[4];
    #pragma unroll
    for (int tp = 0; tp < 4; ++tp)
        cur[tp] = *(const uint2*)(xgS + xoff + tp * 256);

    unsigned short* xout = xnext + (size_t)(bg * 16 + bl) * 256 + dir * 128 + uu;

    __syncthreads();

    for (int s = 0; s < 512; ++s) {
        // prefetch next step's xg fragments
        if (s < 511) {
            #pragma unroll
            for (int tp = 0; tp < 4; ++tp)
                nxt[tp] = *(const uint2*)(xgS + xoff + tstep + tp * 256);
        }
        // B-frags of h(s-1)
        const unsigned short* rb = hbuf[1 - (s & 1)];
        bf16x8 bfr[4];
        #pragma unroll
        for (int kk = 0; kk < 4; ++kk)
            bfr[kk] = *(const bf16x8*)(rb + kk * 512 + lane * 8);
        // acc init from xg (bias already folded in by gemm)
        f32x4 acc[4];
        #pragma unroll
        for (int tp = 0; tp < 4; ++tp) {
            acc[tp].x = bflo(cur[tp].x); acc[tp].y = bfhi(cur[tp].x);
            acc[tp].z = bflo(cur[tp].y); acc[tp].w = bfhi(cur[tp].y);
        }
        #pragma unroll
        for (int kk = 0; kk < 4; ++kk)
            #pragma unroll
            for (int tp = 0; tp < 4; ++tp)
                acc[tp] = __builtin_amdgcn_mfma_f32_16x16x32_bf16(afrag[tp][kk], bfr[kk], acc[tp], 0, 0, 0);
        // nonlinearity: lane owns i/f/g/o of its 4 units
        unsigned short hp[4];
        #pragma unroll
        for (int r = 0; r < 4; ++r) {
            float iv = acc[0][r], fv = acc[1][r], gv = acc[2][r], ov = acc[3][r];
            float cc = fsig(fv) * c[r] + fsig(iv) * ftanh(gv);
            c[r] = cc;
            float h = fsig(ov) * ftanh(cc);
            hp[r] = f2bf(h);
        }
        const int t = dir ? (511 - s) : s;
        ushort4 hv = make_ushort4(hp[0], hp[1], hp[2], hp[3]);
        *(ushort4*)(&hbuf[s & 1][hwoff]) = hv;          // h(s) into frag layout
        *(ushort4*)(xout + (size_t)t * 64 * 256) = hv;  // next layer's input
        xoff += tstep;
        #pragma unroll
        for (int tp = 0; tp < 4; ++tp) cur[tp] = nxt[tp];
        __syncthreads();
    }
}

// ---------- emissions: [MM][8] = x2(bf16) @ h2t_w^T + h2t_b (time-major rows) ----------
__global__ void emis_kernel(const unsigned short* __restrict__ x2,
                            const float* __restrict__ h2t_w,
                            const float* __restrict__ h2t_b,
                            float* __restrict__ emis)
{
    int idx = blockIdx.x * 256 + threadIdx.x;   // m*8 + tag
    int m = idx >> 3, tag = idx & 7;
    const unsigned short* xr = x2 + (size_t)m * 256;
    const float* wr = h2t_w + (size_t)tag * 256;
    float a0 = 0.f, a1 = 0.f, a2 = 0.f, a3 = 0.f;
    #pragma unroll 4
    for (int k = 0; k < 256; k += 8) {
        uint4 xv = *(const uint4*)(xr + k);
        float4 w0 = *(const float4*)(wr + k);
        float4 w1 = *(const float4*)(wr + k + 4);
        a0 += bflo(xv.x) * w0.x + bfhi(xv.x) * w0.y;
        a1 += bflo(xv.y) * w0.z + bfhi(xv.y) * w0.w;
        a2 += bflo(xv.z) * w1.x + bfhi(xv.z) * w1.y;
        a3 += bflo(xv.w) * w1.z + bfhi(xv.w) * w1.w;
    }
    emis[idx] = h2t_b[tag] + ((a0 + a1) + (a2 + a3));
}

// ---------- CRF: per-sample partition (8x8 = 64 lanes) + gold score ----------
// emis is time-major: element (b,t,j) at emis[(t*64+b)*8 + j]
__global__ void crf_kernel(const float* __restrict__ emis,
                           const int* __restrict__ tags,     // [BB][TT] b-major
                           const float* __restrict__ trans,  // [8][8]
                           float* __restrict__ partials)     // [BB]
{
    const int b = blockIdx.x;
    const int l = threadIdx.x;                 // (i = l>>3, j = l&7)
    const float* eb = emis + (size_t)b * 8;    // stride per t = 512 floats
    const int i = l >> 3, j = l & 7;
    const float tij = trans[i * 8 + j];

    float fv = eb[i];
    for (int t = 1; t < TT; ++t) {
        float v = fv + tij + eb[(size_t)t * 512 + j];
        float m = v;
        m = fmaxf(m, __shfl_xor(m, 8));
        m = fmaxf(m, __shfl_xor(m, 16));
        m = fmaxf(m, __shfl_xor(m, 32));
        float e = __expf(v - m);
        e += __shfl_xor(e, 8);
        e += __shfl_xor(e, 16);
        e += __shfl_xor(e, 32);
        float fvj = m + __logf(e);
        fv = __shfl(fvj, i);
    }
    float x = ((l & 7) == 0) ? fv : -1e30f;
    float m2 = x;
    #pragma unroll
    for (int d = 1; d < 64; d <<= 1) m2 = fmaxf(m2, __shfl_xor(m2, d));
    float e2 = ((l & 7) == 0) ? __expf(x - m2) : 0.f;
    #pragma unroll
    for (int d = 1; d < 64; d <<= 1) e2 += __shfl_xor(e2, d);
    float partition = m2 + __logf(e2);

    const int* tg = tags + (size_t)b * TT;
    float sc = 0.f;
    for (int t = l; t < TT; t += 64) sc += eb[(size_t)t * 512 + tg[t]];
    for (int t = l + 1; t < TT; t += 64) sc += trans[tg[t - 1] * 8 + tg[t]];
    #pragma unroll
    for (int d = 1; d < 64; d <<= 1) sc += __shfl_xor(sc, d);

    if (l == 0) partials[b] = sc - partition;
}

__global__ void final_kernel(const float* __restrict__ partials, float* __restrict__ out)
{
    int l = threadIdx.x;
    float v = partials[l];
    #pragma unroll
    for (int d = 1; d < 64; d <<= 1) v += __shfl_xor(v, d);
    if (l == 0) out[0] = -v / 64.f;
}

// ---------- launch ----------
extern "C" void kernel_launch(void* const* d_in, const int* in_sizes, int n_in,
                              void* d_out, int out_size, void* d_ws, size_t ws_size,
                              hipStream_t stream)
{
    const int*   sentences = (const int*)d_in[0];
    const int*   tags      = (const int*)d_in[1];
    const float* embedding = (const float*)d_in[2];
    const float* w_ih_l0   = (const float*)d_in[3];
    const float* w_hh_l0   = (const float*)d_in[4];
    const float* b_ih_l0   = (const float*)d_in[5];
    const float* b_hh_l0   = (const float*)d_in[6];
    const float* w_ih_l0r  = (const float*)d_in[7];
    const float* w_hh_l0r  = (const float*)d_in[8];
    const float* b_ih_l0r  = (const float*)d_in[9];
    const float* b_hh_l0r  = (const float*)d_in[10];
    const float* w_ih_l1   = (const float*)d_in[11];
    const float* w_hh_l1   = (const float*)d_in[12];
    const float* b_ih_l1   = (const float*)d_in[13];
    const float* b_hh_l1   = (const float*)d_in[14];
    const float* w_ih_l1r  = (const float*)d_in[15];
    const float* w_hh_l1r  = (const float*)d_in[16];
    const float* b_ih_l1r  = (const float*)d_in[17];
    const float* b_hh_l1r  = (const float*)d_in[18];
    const float* h2t_w     = (const float*)d_in[19];
    const float* h2t_b     = (const float*)d_in[20];
    const float* trans     = (const float*)d_in[21];

    char* ws = (char*)d_ws;
    unsigned short* xgS   = (unsigned short*)(ws);                // 67,108,864 B
    unsigned short* x0    = (unsigned short*)(ws + 67108864);     //  8,388,608 B
    unsigned short* x1    = (unsigned short*)(ws + 75497472);     // 16,777,216 B
    unsigned short* x2    = x1;                                   // aliases x1 (dead by then)
    unsigned short* W0c   = (unsigned short*)(ws + 92274688);     //    262,144 B
    unsigned short* W1c   = (unsigned short*)(ws + 92536832);     //    524,288 B
    unsigned short* Whh0c = (unsigned short*)(ws + 93061120);     //    262,144 B
    unsigned short* Whh1c = (unsigned short*)(ws + 93323264);     //    262,144 B
    float* bias0          = (float*)(ws + 93585408);              //      4,096 B
    float* bias1          = (float*)(ws + 93589504);              //      4,096 B
    float* emis           = (float*)(ws + 93593600);              //  1,048,576 B
    float* partials       = (float*)(ws + 94642176);              //        256 B
    (void)ws_size; (void)in_sizes; (void)n_in; (void)out_size;

    prep_kernel<<<4744, 256, 0, stream>>>(sentences, embedding,
        w_ih_l0, w_ih_l0r, w_ih_l1, w_ih_l1r,
        w_hh_l0, w_hh_l0r, w_hh_l1, w_hh_l1r,
        b_ih_l0, b_hh_l0, b_ih_l0r, b_hh_l0r,
        b_ih_l1, b_hh_l1, b_ih_l1r, b_hh_l1r,
        x0, W0c, W1c, Whh0c, Whh1c, bias0, bias1);

    gemm_xg<<<dim3(8, 256), 256, 0, stream>>>(W0c, x0, bias0, xgS, 128);
    lstm_scan_mfma<<<8, 512, 0, stream>>>(xgS, Whh0c, x1);
    gemm_xg<<<dim3(8, 256), 256, 0, stream>>>(W1c, x1, bias1, xgS, 256);
    lstm_scan_mfma<<<8, 512, 0, stream>>>(xgS, Whh1c, x2);
    emis_kernel<<<1024, 256, 0, stream>>>(x2, h2t_w, h2t_b, emis);
    crf_kernel<<<64, 64, 0, stream>>>(emis, tags, trans, partials);
    final_kernel<<<1, 64, 0, stream>>>(partials, (float*)d_out);
}

// Round 3
// 794.138 us; speedup vs baseline: 2.4552x; 1.6772x over previous
//
#include <hip/hip_runtime.h>
#include <cstdint>
#include <cstddef>

// ---------- types / helpers ----------
typedef __attribute__((ext_vector_type(8))) short bf16x8;   // 8 bf16 = 4 VGPRs (MFMA A/B frag)
typedef __attribute__((ext_vector_type(4))) float f32x4;    // MFMA C/D frag

__device__ __forceinline__ unsigned short f2bf(float x) {
    union { float f; unsigned u; } v; v.f = x;
    unsigned r = (v.u + 0x7fffu + ((v.u >> 16) & 1u)) >> 16;   // RNE, inputs finite
    return (unsigned short)r;
}
__device__ __forceinline__ float bflo(unsigned u){ union{unsigned i;float f;}v; v.i = u << 16;        return v.f; }
__device__ __forceinline__ float bfhi(unsigned u){ union{unsigned i;float f;}v; v.i = u & 0xffff0000u; return v.f; }
__device__ __forceinline__ float frcp(float x){ return __builtin_amdgcn_rcpf(x); }

// lgkm-only barrier: keeps global prefetch loads in flight across the sync (CK pattern)
#define BARRIER_LGKM() asm volatile("s_waitcnt lgkmcnt(0)\n\ts_barrier" ::: "memory")

#define BB 64
#define TT 512
#define MM (BB*TT)     // 32768 rows (time-major: m = t*64 + b)
#define NG 1024        // 4H * 2 directions (permuted gate order)

// Gate permutation (per direction): g2 = w*64 + tile*16 + uq*4 + gtype
//   unit = w*16 + tile*4 + uq ; orig row = gtype*128 + unit
// -> in MFMA D (row_in_tile = quad*4 + reg), reg index IS the gate type, so one
//    lane's 4 C-regs of tile d hold i/f/g/o of one unit.
__device__ __forceinline__ int perm_orig(int g2) {
    return (g2 & 3) * 128 + (g2 >> 6) * 16 + ((g2 >> 4) & 3) * 4 + ((g2 >> 2) & 3);
}

// ---------- prep: gather (time-major) + permuted weight/bias convert ----------
__global__ void prep_kernel(
    const int* __restrict__ sentences, const float* __restrict__ emb,
    const float* __restrict__ w_ih_l0, const float* __restrict__ w_ih_l0r,
    const float* __restrict__ w_ih_l1, const float* __restrict__ w_ih_l1r,
    const float* __restrict__ w_hh_l0, const float* __restrict__ w_hh_l0r,
    const float* __restrict__ w_hh_l1, const float* __restrict__ w_hh_l1r,
    const float* __restrict__ b_ih_l0, const float* __restrict__ b_hh_l0,
    const float* __restrict__ b_ih_l0r, const float* __restrict__ b_hh_l0r,
    const float* __restrict__ b_ih_l1, const float* __restrict__ b_hh_l1,
    const float* __restrict__ b_ih_l1r, const float* __restrict__ b_hh_l1r,
    unsigned short* __restrict__ x0, unsigned short* __restrict__ W0c,
    unsigned short* __restrict__ W1c,
    unsigned short* __restrict__ Whh0c, unsigned short* __restrict__ Whh1c,
    float* __restrict__ bias0, float* __restrict__ bias1)
{
    int blk = blockIdx.x;
    if (blk < 4096) {                       // gather: 32768 x 128, time-major rows
        int t4 = blk * 256 + threadIdx.x;
        int e4 = t4 * 4; int m = e4 >> 7; int k = e4 & 127;
        int tt = m >> 6, b = m & 63;
        int s = sentences[b * 512 + tt];
        float4 v = *(const float4*)(emb + (size_t)s * 128 + k);
        *(ushort4*)(x0 + (size_t)m * 128 + k) =
            make_ushort4(f2bf(v.x), f2bf(v.y), f2bf(v.z), f2bf(v.w));
    } else if (blk < 4224) {                // W0c: 1024 x 128, permuted rows
        int t4 = (blk - 4096) * 256 + threadIdx.x;
        int e4 = t4 * 4; int n = e4 >> 7; int k = e4 & 127;
        int dir = n >> 9; int orig = perm_orig(n & 511);
        const float* src = dir ? w_ih_l0r : w_ih_l0;
        float4 v = *(const float4*)(src + (size_t)orig * 128 + k);
        *(ushort4*)(W0c + (size_t)n * 128 + k) =
            make_ushort4(f2bf(v.x), f2bf(v.y), f2bf(v.z), f2bf(v.w));
    } else if (blk < 4480) {                // W1c: 1024 x 256, permuted rows
        int t4 = (blk - 4224) * 256 + threadIdx.x;
        int e4 = t4 * 4; int n = e4 >> 8; int k = e4 & 255;
        int dir = n >> 9; int orig = perm_orig(n & 511);
        const float* src = dir ? w_ih_l1r : w_ih_l1;
        float4 v = *(const float4*)(src + (size_t)orig * 256 + k);
        *(ushort4*)(W1c + (size_t)n * 256 + k) =
            make_ushort4(f2bf(v.x), f2bf(v.y), f2bf(v.z), f2bf(v.w));
    } else if (blk < 4608) {                // Whh0c: [2][512][128] bf16, permuted rows
        int t4 = (blk - 4480) * 256 + threadIdx.x;
        int e4 = t4 * 4; int n = e4 >> 7; int k = e4 & 127;
        int dir = n >> 9; int orig = perm_orig(n & 511);
        const float* src = dir ? w_hh_l0r : w_hh_l0;
        float4 v = *(const float4*)(src + (size_t)orig * 128 + k);
        *(ushort4*)(Whh0c + (size_t)n * 128 + k) =
            make_ushort4(f2bf(v.x), f2bf(v.y), f2bf(v.z), f2bf(v.w));
    } else if (blk < 4736) {                // Whh1c
        int t4 = (blk - 4608) * 256 + threadIdx.x;
        int e4 = t4 * 4; int n = e4 >> 7; int k = e4 & 127;
        int dir = n >> 9; int orig = perm_orig(n & 511);
        const float* src = dir ? w_hh_l1r : w_hh_l1;
        float4 v = *(const float4*)(src + (size_t)orig * 128 + k);
        *(ushort4*)(Whh1c + (size_t)n * 128 + k) =
            make_ushort4(f2bf(v.x), f2bf(v.y), f2bf(v.z), f2bf(v.w));
    } else {                                // biases: 2048 values, permuted
        int t = (blk - 4736) * 256 + threadIdx.x;
        int n = t & 1023;
        int dir = n >> 9; int orig = perm_orig(n & 511);
        if (t < 1024)
            bias0[n] = dir ? (b_ih_l0r[orig] + b_hh_l0r[orig]) : (b_ih_l0[orig] + b_hh_l0[orig]);
        else
            bias1[n] = dir ? (b_ih_l1r[orig] + b_hh_l1r[orig]) : (b_ih_l1[orig] + b_hh_l1[orig]);
    }
}

// ---------- GEMM: xg[m][n] = sum_k X[m][k]*W[n][k] + bias[n]  (bf16 MFMA) ----------
// Epilogue writes xgS in scan layout: ushort idx = (((t2*8 + w)*16 + u16)*64 + b)*4 + gtype
// where t2 = t*2+dir, u16 = i*4+quad (unit offset within wave), gtype = reg.
__global__ __launch_bounds__(256, 2) void gemm_xg(
    const unsigned short* __restrict__ W,   // [NG][K] permuted rows
    const unsigned short* __restrict__ X,   // [MM][K] time-major
    const float* __restrict__ bias,         // [NG] permuted
    unsigned short* __restrict__ xgS,       // scan layout, 64 MB
    int K)
{
    __shared__ unsigned short sW[128 * 32];
    __shared__ unsigned short sX[128 * 32];
    const int tid  = threadIdx.x;
    const int lane = tid & 63;
    const int wid  = tid >> 6;
    const int w_n  = wid & 1, w_m = wid >> 1;
    const int r16  = lane & 15, quad = lane >> 4;
    const int nTile = blockIdx.x * 128;
    const int mTile = blockIdx.y * 128;

    f32x4 zero = {0.f, 0.f, 0.f, 0.f};
    f32x4 acc[4][4];
    #pragma unroll
    for (int i = 0; i < 4; ++i)
        #pragma unroll
        for (int j = 0; j < 4; ++j) acc[i][j] = zero;

    const int q0 = tid, q1 = tid + 256;
    const int r0 = q0 >> 2, ko0 = (q0 & 3) * 8;
    const int r1 = q1 >> 2, ko1 = (q1 & 3) * 8;

    for (int k0 = 0; k0 < K; k0 += 32) {
        __syncthreads();
        uint4 wv0 = *(const uint4*)(W + (size_t)(nTile + r0) * K + k0 + ko0);
        uint4 wv1 = *(const uint4*)(W + (size_t)(nTile + r1) * K + k0 + ko1);
        uint4 xv0 = *(const uint4*)(X + (size_t)(mTile + r0) * K + k0 + ko0);
        uint4 xv1 = *(const uint4*)(X + (size_t)(mTile + r1) * K + k0 + ko1);
        ((uint4*)sW)[q0] = wv0;
        ((uint4*)sW)[q1] = wv1;
        ((uint4*)sX)[q0] = xv0;
        ((uint4*)sX)[q1] = xv1;
        __syncthreads();
        const bf16x8* sWv = (const bf16x8*)sW;
        const bf16x8* sXv = (const bf16x8*)sX;
        bf16x8 a[4], bx[4];
        #pragma unroll
        for (int i = 0; i < 4; ++i) {
            a[i]  = sWv[(w_n * 64 + i * 16 + r16) * 4 + quad];
            bx[i] = sXv[(w_m * 64 + i * 16 + r16) * 4 + quad];
        }
        #pragma unroll
        for (int i = 0; i < 4; ++i)
            #pragma unroll
            for (int j = 0; j < 4; ++j)
                acc[i][j] = __builtin_amdgcn_mfma_f32_16x16x32_bf16(a[i], bx[j], acc[i][j], 0, 0, 0);
    }

    // epilogue: pack 4 gate-regs (i/f/g/o of one unit) -> one 8B store
    const int w_idx = ((nTile & 511) + w_n * 64) >> 6;
    const int dirn  = nTile >> 9;
    float4 bv[4];
    #pragma unroll
    for (int i = 0; i < 4; ++i)
        bv[i] = *(const float4*)(bias + nTile + w_n * 64 + i * 16 + quad * 4);
    #pragma unroll
    for (int j = 0; j < 4; ++j) {
        int m = mTile + w_m * 64 + j * 16 + r16;
        int t = m >> 6, b = m & 63;
        size_t base = (size_t)((t * 2 + dirn) * 8 + w_idx) * 4096 + (size_t)b * 4;
        #pragma unroll
        for (int i = 0; i < 4; ++i) {
            f32x4 v = acc[i][j];
            ushort4 o = make_ushort4(f2bf(v.x + bv[i].x), f2bf(v.y + bv[i].y),
                                     f2bf(v.z + bv[i].z), f2bf(v.w + bv[i].w));
            *(uint2*)(xgS + base + (size_t)(i * 4 + quad) * 256) = *(uint2*)&o;
        }
    }
}

// ---------- MFMA LSTM scan: 32 blocks (2 dir x 16 batch-groups of 4), 512 threads ----------
// 4 batches duplicated 4x into the 16 MFMA columns; dup-lane d handles tile d, whose
// 4 C-regs are the i/f/g/o gates of unit u = w*16 + d*4 + q. One lgkm-only barrier/step.
__global__ __launch_bounds__(512, 1) void lstm_scan_mfma(
    const unsigned short* __restrict__ xgS,     // [t2][w8][u16][b64][g4]
    const unsigned short* __restrict__ whh_c,   // [2][512 perm rows][128] bf16
    unsigned short* __restrict__ xnext)         // [MM][256], col = dir*128 + u
{
    const int dir = blockIdx.x >> 4;
    const int bg  = blockIdx.x & 15;
    const int tid = threadIdx.x;
    const int w   = tid >> 6;
    const int lane= tid & 63;
    const int q   = lane >> 4;
    const int bl  = lane & 15;
    const int d   = bl >> 2;
    const int b4  = bl & 3;
    const int u   = w * 16 + d * 4 + q;      // original unit index this lane owns
    const int b   = bg * 4 + b4;             // batch

    // weights -> A-frags (register-resident for all 512 steps)
    bf16x8 afrag[4][4];
    {
        const unsigned short* wb = whh_c + (size_t)dir * 65536;
        #pragma unroll
        for (int tile = 0; tile < 4; ++tile)
            #pragma unroll
            for (int kk = 0; kk < 4; ++kk)
                afrag[tile][kk] = *(const bf16x8*)(wb + (size_t)(w * 64 + tile * 16 + bl) * 128 + kk * 32 + q * 8);
    }

    __shared__ unsigned short hbuf[2][512];  // h(4 batches x 128 units) in B-frag order, dbuf
    hbuf[1][tid] = 0;                        // h(-1) = 0

    float c = 0.f;
    const long tstep = dir ? -65536L : 65536L;    // ushorts per t step (2 slices of 32768)
    long xoff = (long)(dir ? 1023 : 0) * 32768 + (long)((w * 16 + d * 4 + q) * 64 + b) * 4;
    const long hstep = dir ? -16384L : 16384L;
    long hoff = (long)(dir ? 511 : 0) * 16384 + (long)b * 256 + dir * 128 + u;

    const int hw  = ((u >> 3) * 4 + b4) * 8 + (u & 7);  // hbuf write idx (k=u, col=b4)
    const int hr0 = (q * 4 + b4) * 8;                   // read base: kk*128 + hr0

    uint2 ring[4];
    #pragma unroll
    for (int i = 0; i < 4; ++i)
        ring[i] = *(const uint2*)(xgS + xoff + i * tstep);

    BARRIER_LGKM();

    for (int it = 0; it < 128; ++it) {
        #pragma unroll
        for (int p = 0; p < 4; ++p) {
            const unsigned short* rb = hbuf[(p & 1) ^ 1];
            bf16x8 bfr[4];
            #pragma unroll
            for (int kk = 0; kk < 4; ++kk)
                bfr[kk] = *(const bf16x8*)(rb + kk * 128 + hr0);

            uint2 xv = ring[p];
            f32x4 gv;
            gv.x = bflo(xv.x); gv.y = bfhi(xv.x);    // i, f
            gv.z = bflo(xv.y); gv.w = bfhi(xv.y);    // g, o
            f32x4 acc[4];
            #pragma unroll
            for (int tile = 0; tile < 4; ++tile) acc[tile] = gv;   // only tile d's C matters

            ring[p] = *(const uint2*)(xgS + xoff + 4 * tstep);     // prefetch (pads cover OOB)
            xoff += tstep;

            #pragma unroll
            for (int kk = 0; kk < 4; ++kk)
                #pragma unroll
                for (int tile = 0; tile < 4; ++tile)
                    acc[tile] = __builtin_amdgcn_mfma_f32_16x16x32_bf16(afrag[tile][kk], bfr[kk], acc[tile], 0, 0, 0);

            f32x4 sel = acc[0];
            sel = (d == 1) ? acc[1] : sel;
            sel = (d == 2) ? acc[2] : sel;
            sel = (d == 3) ? acc[3] : sel;

            float iv = fminf(fmaxf(sel.x, -20.f), 20.f);
            float fv = fminf(fmaxf(sel.y, -20.f), 20.f);
            float gg = fminf(fmaxf(sel.z, -12.f), 12.f);
            float ov = fminf(fmaxf(sel.w, -20.f), 20.f);
            float ei = __expf(-iv), ef = __expf(-fv), eg = __expf(-2.f * gg);
            float t1 = 1.f + ei, t2g = 1.f + eg, t3 = 1.f + ef;
            float pp = t1 * t2g;
            float cn = (c * pp + (1.f - eg) * t3) * frcp(pp * t3);
            c = cn;
            float ccl = fminf(fmaxf(cn, -12.f), 12.f);
            float eo = __expf(-ov), ec = __expf(-2.f * ccl);
            float h = (1.f - ec) * frcp((1.f + eo) * (1.f + ec));
            unsigned short hb = f2bf(h);

            hbuf[p & 1][hw] = hb;
            xnext[hoff] = hb;
            hoff += hstep;
            BARRIER_LGKM();
        }
    }
}

// ---------- emissions: [MM][8] = x2(bf16) @ h2t_w^T + h2t_b (time-major rows) ----------
__global__ void emis_kernel(const unsigned short* __restrict__ x2,
                            const float* __restrict__ h2t_w,
                            const float* __restrict__ h2t_b,
                            float* __restrict__ emis)
{
    int idx = blockIdx.x * 256 + threadIdx.x;   // m*8 + tag
    int m = idx >> 3, tag = idx & 7;
    const unsigned short* xr = x2 + (size_t)m * 256;
    const float* wr = h2t_w + (size_t)tag * 256;
    float a0 = 0.f, a1 = 0.f, a2 = 0.f, a3 = 0.f;
    #pragma unroll 4
    for (int k = 0; k < 256; k += 8) {
        uint4 xv = *(const uint4*)(xr + k);
        float4 w0 = *(const float4*)(wr + k);
        float4 w1 = *(const float4*)(wr + k + 4);
        a0 += bflo(xv.x) * w0.x + bfhi(xv.x) * w0.y;
        a1 += bflo(xv.y) * w0.z + bfhi(xv.y) * w0.w;
        a2 += bflo(xv.z) * w1.x + bfhi(xv.z) * w1.y;
        a3 += bflo(xv.w) * w1.z + bfhi(xv.w) * w1.w;
    }
    emis[idx] = h2t_b[tag] + ((a0 + a1) + (a2 + a3));
}

// ---------- CRF: 8 samples per wave; lane = (sample_slot, tag j) ----------
// emis is time-major: (b,t,j) at emis[(t*64+b)*8 + j]
__global__ void crf_kernel(const float* __restrict__ emis,
                           const int* __restrict__ tags,     // [BB][TT]
                           const float* __restrict__ trans,  // [8][8]
                           float* __restrict__ partials)     // [BB]
{
    const int l = threadIdx.x;
    const int sl = l >> 3, j = l & 7, sl8 = sl * 8;
    const int b = blockIdx.x * 8 + sl;
    float T[8];
    #pragma unroll
    for (int i = 0; i < 8; ++i) T[i] = trans[i * 8 + j];   // column j

    const float* eb = emis + (size_t)b * 8 + j;            // e(t) = eb[t*512]
    float fv = eb[0];
    float e1 = eb[512], e2 = eb[1024];

    auto step = [&](float e_t) {
        float v0 = __shfl(fv, sl8 + 0) + T[0];
        float v1 = __shfl(fv, sl8 + 1) + T[1];
        float v2 = __shfl(fv, sl8 + 2) + T[2];
        float v3 = __shfl(fv, sl8 + 3) + T[3];
        float v4 = __shfl(fv, sl8 + 4) + T[4];
        float v5 = __shfl(fv, sl8 + 5) + T[5];
        float v6 = __shfl(fv, sl8 + 6) + T[6];
        float v7 = __shfl(fv, sl8 + 7) + T[7];
        float m = fmaxf(fmaxf(fmaxf(v0, v1), fmaxf(v2, v3)),
                        fmaxf(fmaxf(v4, v5), fmaxf(v6, v7)));
        float s = __expf(v0 - m) + __expf(v1 - m) + __expf(v2 - m) + __expf(v3 - m)
                + __expf(v4 - m) + __expf(v5 - m) + __expf(v6 - m) + __expf(v7 - m);
        fv = m + __logf(s) + e_t;
    };

    int t = 1;
    for (int it = 0; it < 255; ++it) {          // t = 1..510 in pairs, e prefetched 2 ahead
        step(e1); e1 = eb[(size_t)(t + 2) * 512]; ++t;
        step(e2); e2 = eb[(size_t)(t + 2) * 512]; ++t;   // t+2=512 read lands in pad
    }
    step(e1);                                   // t = 511

    // partition = lse_j fv[j] within the 8-lane group
    float m2 = fv;
    m2 = fmaxf(m2, __shfl_xor(m2, 1));
    m2 = fmaxf(m2, __shfl_xor(m2, 2));
    m2 = fmaxf(m2, __shfl_xor(m2, 4));
    float e2s = __expf(fv - m2);
    e2s += __shfl_xor(e2s, 1);
    e2s += __shfl_xor(e2s, 2);
    e2s += __shfl_xor(e2s, 4);
    float partition = m2 + __logf(e2s);

    // gold score for this sample (8 lanes cooperate)
    const int* tg = tags + (size_t)b * TT;
    float sc = 0.f;
    for (int tt = j; tt < TT; tt += 8) {
        int tag = tg[tt];
        sc += emis[((size_t)tt * 64 + b) * 8 + tag];
        if (tt > 0) sc += trans[tg[tt - 1] * 8 + tag];
    }
    sc += __shfl_xor(sc, 1);
    sc += __shfl_xor(sc, 2);
    sc += __shfl_xor(sc, 4);
    if (j == 0) partials[b] = sc - partition;
}

__global__ void final_kernel(const float* __restrict__ partials, float* __restrict__ out)
{
    int l = threadIdx.x;
    float v = partials[l];
    #pragma unroll
    for (int d = 1; d < 64; d <<= 1) v += __shfl_xor(v, d);
    if (l == 0) out[0] = -v / 64.f;
}

// ---------- launch ----------
extern "C" void kernel_launch(void* const* d_in, const int* in_sizes, int n_in,
                              void* d_out, int out_size, void* d_ws, size_t ws_size,
                              hipStream_t stream)
{
    const int*   sentences = (const int*)d_in[0];
    const int*   tags      = (const int*)d_in[1];
    const float* embedding = (const float*)d_in[2];
    const float* w_ih_l0   = (const float*)d_in[3];
    const float* w_hh_l0   = (const float*)d_in[4];
    const float* b_ih_l0   = (const float*)d_in[5];
    const float* b_hh_l0   = (const float*)d_in[6];
    const float* w_ih_l0r  = (const float*)d_in[7];
    const float* w_hh_l0r  = (const float*)d_in[8];
    const float* b_ih_l0r  = (const float*)d_in[9];
    const float* b_hh_l0r  = (const float*)d_in[10];
    const float* w_ih_l1   = (const float*)d_in[11];
    const float* w_hh_l1   = (const float*)d_in[12];
    const float* b_ih_l1   = (const float*)d_in[13];
    const float* b_hh_l1   = (const float*)d_in[14];
    const float* w_ih_l1r  = (const float*)d_in[15];
    const float* w_hh_l1r  = (const float*)d_in[16];
    const float* b_ih_l1r  = (const float*)d_in[17];
    const float* b_hh_l1r  = (const float*)d_in[18];
    const float* h2t_w     = (const float*)d_in[19];
    const float* h2t_b     = (const float*)d_in[20];
    const float* trans     = (const float*)d_in[21];

    char* ws = (char*)d_ws;
    // pad0 512K | xgS 64M | pad1 512K | x0 8M | x1 16M | W0c | W1c | Whh0 | Whh1 | b0 | b1 | emis 1M+8K pad | partials
    unsigned short* xgS   = (unsigned short*)(ws + 524288);
    unsigned short* x0    = (unsigned short*)(ws + 68157440);
    unsigned short* x1    = (unsigned short*)(ws + 76546048);
    unsigned short* x2    = x1;                               // aliases x1 (dead by then)
    unsigned short* W0c   = (unsigned short*)(ws + 93323264);
    unsigned short* W1c   = (unsigned short*)(ws + 93585408);
    unsigned short* Whh0c = (unsigned short*)(ws + 94109696);
    unsigned short* Whh1c = (unsigned short*)(ws + 94371840);
    float* bias0          = (float*)(ws + 94633984);
    float* bias1          = (float*)(ws + 94638080);
    float* emis           = (float*)(ws + 94642176);
    float* partials       = (float*)(ws + 95698944);
    (void)ws_size; (void)in_sizes; (void)n_in; (void)out_size;

    prep_kernel<<<4744, 256, 0, stream>>>(sentences, embedding,
        w_ih_l0, w_ih_l0r, w_ih_l1, w_ih_l1r,
        w_hh_l0, w_hh_l0r, w_hh_l1, w_hh_l1r,
        b_ih_l0, b_hh_l0, b_ih_l0r, b_hh_l0r,
        b_ih_l1, b_hh_l1, b_ih_l1r, b_hh_l1r,
        x0, W0c, W1c, Whh0c, Whh1c, bias0, bias1);

    gemm_xg<<<dim3(8, 256), 256, 0, stream>>>(W0c, x0, bias0, xgS, 128);
    lstm_scan_mfma<<<32, 512, 0, stream>>>(xgS, Whh0c, x1);
    gemm_xg<<<dim3(8, 256), 256, 0, stream>>>(W1c, x1, bias1, xgS, 256);
    lstm_scan_mfma<<<32, 512, 0, stream>>>(xgS, Whh1c, x2);
    emis_kernel<<<1024, 256, 0, stream>>>(x2, h2t_w, h2t_b, emis);
    crf_kernel<<<8, 64, 0, stream>>>(emis, tags, trans, partials);
    final_kernel<<<1, 64, 0, stream>>>(partials, (float*)d_out);
}